// Round 3
// baseline (831.165 us; speedup 1.0000x reference)
//
#include <hip/hip_runtime.h>

typedef __bf16 bf16x8 __attribute__((ext_vector_type(8)));
typedef __bf16 bf16x4 __attribute__((ext_vector_type(4)));
typedef float f32x4 __attribute__((ext_vector_type(4)));

__device__ __forceinline__ f32x4 mfma16(bf16x8 a, bf16x8 b, f32x4 c) {
  return __builtin_amdgcn_mfma_f32_16x16x32_bf16(a, b, c, 0, 0, 0);
}

__device__ __forceinline__ bf16x8 cvt8(float4 a, float4 b) {
  bf16x8 h;
  h[0] = (__bf16)a.x; h[1] = (__bf16)a.y; h[2] = (__bf16)a.z; h[3] = (__bf16)a.w;
  h[4] = (__bf16)b.x; h[5] = (__bf16)b.y; h[6] = (__bf16)b.z; h[7] = (__bf16)b.w;
  return h;
}

// ---------------------------------------------------------------------------
// Kernel 1: projection GEMM (NT): O[m][n] = (sum_k A[m][k]*W[n][k] + bias[n])*scale
// A: f32 [8192][1024], W: f32 [1024][1024] (row-major [n][k]) -> bf16 out.
// OUT_MODE 0: row-major [8192][1024].  OUT_MODE 1: vpT layout [B][H][D][S].
// ---------------------------------------------------------------------------
template<int OUT_MODE>
__global__ __launch_bounds__(256, 2)
void proj_gemm(const float* __restrict__ A, const float* __restrict__ W,
               const float* __restrict__ bias, __bf16* __restrict__ O, float scale)
{
  constexpr int LDT = 40;  // padded bf16 stride (80B rows) to break LDS bank conflicts
  __shared__ __align__(16) __bf16 lA[128 * LDT];
  __shared__ __align__(16) __bf16 lB[128 * LDT];
  const int tid = threadIdx.x;
  const int lane = tid & 63;
  const int wid = tid >> 6;
  const int bn0 = blockIdx.x * 128;
  const int bm0 = blockIdx.y * 128;
  const int wm = (wid >> 1) * 64;
  const int wn = (wid & 1) * 64;
  const int lr = lane & 15;
  const int lk = (lane >> 4) * 8;

  f32x4 acc[4][4];
  #pragma unroll
  for (int i = 0; i < 4; ++i)
    #pragma unroll
    for (int j = 0; j < 4; ++j) acc[i][j] = (f32x4){0.f, 0.f, 0.f, 0.f};

  const int rs = tid >> 2;        // 0..63
  const int cs = (tid & 3) * 8;   // 0,8,16,24

  for (int k0 = 0; k0 < 1024; k0 += 32) {
    #pragma unroll
    for (int rr = 0; rr < 2; ++rr) {
      const int r = rs + rr * 64;
      const float* sa = A + (size_t)(bm0 + r) * 1024 + k0 + cs;
      const float* sb = W + (size_t)(bn0 + r) * 1024 + k0 + cs;
      float4 a0 = *(const float4*)sa;
      float4 a1 = *(const float4*)(sa + 4);
      float4 b0 = *(const float4*)sb;
      float4 b1 = *(const float4*)(sb + 4);
      *(bf16x8*)&lA[r * LDT + cs] = cvt8(a0, a1);
      *(bf16x8*)&lB[r * LDT + cs] = cvt8(b0, b1);
    }
    __syncthreads();
    bf16x8 aF[4], bF[4];
    #pragma unroll
    for (int t = 0; t < 4; ++t) {
      aF[t] = *(const bf16x8*)&lA[(wm + t * 16 + lr) * LDT + lk];
      bF[t] = *(const bf16x8*)&lB[(wn + t * 16 + lr) * LDT + lk];
    }
    #pragma unroll
    for (int mt = 0; mt < 4; ++mt)
      #pragma unroll
      for (int nt = 0; nt < 4; ++nt)
        acc[mt][nt] = mfma16(aF[mt], bF[nt], acc[mt][nt]);
    __syncthreads();
  }

  const int col = lane & 15;
  const int rb = (lane >> 4) * 4;
  #pragma unroll
  for (int nt = 0; nt < 4; ++nt) {
    const int n = bn0 + wn + nt * 16 + col;
    const float bvv = bias[n];
    #pragma unroll
    for (int mt = 0; mt < 4; ++mt) {
      #pragma unroll
      for (int i = 0; i < 4; ++i) {
        const int m = bm0 + wm + mt * 16 + rb + i;
        const float v = (acc[mt][nt][i] + bvv) * scale;
        if constexpr (OUT_MODE == 0) {
          O[(size_t)m * 1024 + n] = (__bf16)v;
        } else {
          // vpT[b][h][d][s]: b=m>>10, s=m&1023, h=n>>6, d=n&63
          const int bb = m >> 10, s = m & 1023, hh = n >> 6, dd = n & 63;
          O[((size_t)((bb * 16 + hh) * 64 + dd)) * 1024 + s] = (__bf16)v;
        }
      }
    }
  }
}

// ---------------------------------------------------------------------------
// Kernel 2: attention, swapped-QK^T lane-local softmax, no P LDS round trip.
// Block = (b, 16 t-rows), 4 waves; wave w owns s-slice [w*256, w*256+256).
// mfma(K, Q) -> D[s][t]: lane holds t=lane&15, s=(lane>>4)*4+i per j-chunk,
// i.e. 64 s-values for ONE t-row => row softmax is in-register + 2 shfl_xor
// + tiny cross-wave LDS reduce. P feeds PV A-fragments directly via the
// bijective k-map {s=32m+4g+i <-> k=8g+i ; s=32m+16+4g+i <-> k=8g+4+i}
// (no shuffles, no P staging). Partial o combined across waves via 17-padded
// LDS tile. attn_max kept packed bf16 in regs, written coalesced at the end.
// ---------------------------------------------------------------------------
__global__ __launch_bounds__(256, 3)
void attn_kernel(const __bf16* __restrict__ qp, const __bf16* __restrict__ kp,
                 const __bf16* __restrict__ vpT, __bf16* __restrict__ rep,
                 float* __restrict__ amax_out)
{
  __shared__ float redm[16 * 4];
  __shared__ float reds[16 * 4];
  __shared__ __align__(16) float ob[4 * 64 * 17];  // [wave][d][t] padded

  const int bid = blockIdx.x;
  const int b = bid & 7;          // same-b blocks -> same XCD (L2 reuse of kp/vpT)
  const int t0 = (bid >> 3) * 16;
  const int tid = threadIdx.x;
  const int lane = tid & 63;
  const int w = tid >> 6;         // wave owns s-slice [w*256, w*256+256)
  const int lr = lane & 15;
  const int g = lane >> 4;

  bf16x4 am4[16];                 // running max over heads, packed bf16
  #pragma unroll
  for (int j = 0; j < 16; ++j)
    #pragma unroll
    for (int i = 0; i < 4; ++i) am4[j][i] = (__bf16)0.f;

  const size_t qrow = (size_t)(b * 1024 + t0 + lr) * 1024;

  for (int h = 0; h < 16; ++h) {
    // ---- Q B-fragment (n = t = lr) ----
    const __bf16* qb = qp + qrow + h * 64 + g * 8;
    const bf16x8 bF0 = *(const bf16x8*)qb;
    const bf16x8 bF1 = *(const bf16x8*)(qb + 32);

    // ---- QK^T swapped: p[j] = D[s][t], s = w*256 + j*16 + g*4 + i, t = lr ----
    f32x4 p[16];
    #pragma unroll 4
    for (int j = 0; j < 16; ++j) {
      const int s0 = w * 256 + j * 16;
      const __bf16* kb = kp + (size_t)(b * 1024 + s0 + lr) * 1024 + h * 64 + g * 8;
      const bf16x8 aF0 = *(const bf16x8*)kb;
      const bf16x8 aF1 = *(const bf16x8*)(kb + 32);
      f32x4 d = {0.f, 0.f, 0.f, 0.f};
      d = mfma16(aF0, bF0, d);
      d = mfma16(aF1, bF1, d);
      p[j] = d;
    }

    // ---- row max: in-register (lane-local!) + 2 shfl + cross-wave LDS ----
    f32x4 m4 = p[0];
    #pragma unroll
    for (int j = 1; j < 16; ++j)
      #pragma unroll
      for (int i = 0; i < 4; ++i) m4[i] = fmaxf(m4[i], p[j][i]);
    float mm = fmaxf(fmaxf(m4[0], m4[1]), fmaxf(m4[2], m4[3]));
    mm = fmaxf(mm, __shfl_xor(mm, 16));
    mm = fmaxf(mm, __shfl_xor(mm, 32));
    if (lane < 16) redm[lr * 4 + w] = mm;
    __syncthreads();  // B1
    const f32x4 mv = *(const f32x4*)&redm[lr * 4];
    const float mfin = fmaxf(fmaxf(mv[0], mv[1]), fmaxf(mv[2], mv[3]));

    // ---- exp + sum (lane-local) ----
    f32x4 s4 = {0.f, 0.f, 0.f, 0.f};
    #pragma unroll
    for (int j = 0; j < 16; ++j) {
      #pragma unroll
      for (int i = 0; i < 4; ++i) {
        const float e = __expf(p[j][i] - mfin);
        p[j][i] = e;
        s4[i] += e;
      }
    }
    float ss = (s4[0] + s4[1]) + (s4[2] + s4[3]);
    ss += __shfl_xor(ss, 16);
    ss += __shfl_xor(ss, 32);
    if (lane < 16) reds[lr * 4 + w] = ss;
    __syncthreads();  // B2
    const f32x4 sv = *(const f32x4*)&reds[lr * 4];
    const float inv = 1.f / ((sv[0] + sv[1]) + (sv[2] + sv[3]));

    // ---- running attn_max (normalized), packed bf16 ----
    #pragma unroll
    for (int j = 0; j < 16; ++j) {
      #pragma unroll
      for (int i = 0; i < 4; ++i) {
        const float pn = p[j][i] * inv;
        const float o = (float)am4[j][i];
        am4[j][i] = (__bf16)fmaxf(o, pn);
      }
    }

    // ---- PV: po[dc][i] = sum_s P[t=g*4+i... wait: A=P (m=t=lr), B=V (n=d=lr)
    //      D[m=t][n=d]: row t = g*4+i, col d = dc*16 + lr. Unnormalized. ----
    f32x4 po[4];
    #pragma unroll
    for (int dc = 0; dc < 4; ++dc) po[dc] = (f32x4){0.f, 0.f, 0.f, 0.f};
    const __bf16* vb0 = vpT + ((size_t)((b * 16 + h) * 64) + lr) * 1024 + w * 256;
    #pragma unroll 2
    for (int m = 0; m < 8; ++m) {
      bf16x8 av;
      #pragma unroll
      for (int i = 0; i < 4; ++i) {
        av[i] = (__bf16)p[2 * m][i];
        av[4 + i] = (__bf16)p[2 * m + 1][i];
      }
      const int so = m * 32 + g * 4;
      #pragma unroll
      for (int dc = 0; dc < 4; ++dc) {
        const __bf16* vb = vb0 + (size_t)(dc * 16) * 1024;
        const bf16x4 b0 = *(const bf16x4*)(vb + so);
        const bf16x4 b1 = *(const bf16x4*)(vb + so + 16);
        bf16x8 bv;
        #pragma unroll
        for (int i = 0; i < 4; ++i) { bv[i] = b0[i]; bv[4 + i] = b1[i]; }
        po[dc] = mfma16(av, bv, po[dc]);
      }
    }

    // ---- cross-wave o combine via LDS (ob[w][d][t], pad 17) ----
    #pragma unroll
    for (int dc = 0; dc < 4; ++dc)
      *(f32x4*)&ob[(w * 64 + dc * 16 + lr) * 17 + g * 4] = po[dc];
    __syncthreads();  // B3
    f32x4 fin = {0.f, 0.f, 0.f, 0.f};
    #pragma unroll
    for (int w2 = 0; w2 < 4; ++w2) {
      const f32x4 t4 = *(const f32x4*)&ob[(w2 * 64 + w * 16 + lr) * 17 + g * 4];
      #pragma unroll
      for (int i = 0; i < 4; ++i) fin[i] += t4[i];
    }
    // inv for rows t = g*4+i lives in lane lr' = g*4+i (same wave): bpermute
    #pragma unroll
    for (int i = 0; i < 4; ++i) {
      const float iv = __shfl(inv, g * 4 + i);
      rep[(size_t)(b * 1024 + t0 + g * 4 + i) * 1024 + h * 64 + w * 16 + lr] =
          (__bf16)(fin[i] * iv);
    }
  }

  // ---- write attn_max: lane covers t = lr, s = w*256 + j*16 + g*4 + i ----
  const size_t arow = (size_t)(b * 1024 + t0 + lr) * 1024;
  #pragma unroll
  for (int j = 0; j < 16; ++j) {
    f32x4 v;
    #pragma unroll
    for (int i = 0; i < 4; ++i) v[i] = (float)am4[j][i];
    *(f32x4*)&amax_out[arow + w * 256 + j * 16 + g * 4] = v;
  }
}

// ---------------------------------------------------------------------------
// Kernel 3: out projection: O[m][n] = sum_k rep[m][k]*Wo[n][k] + bo[n]  (f32 out)
// ---------------------------------------------------------------------------
__global__ __launch_bounds__(256, 2)
void out_gemm(const __bf16* __restrict__ A, const float* __restrict__ W,
              const float* __restrict__ bias, float* __restrict__ O)
{
  constexpr int LDT = 40;
  __shared__ __align__(16) __bf16 lA[128 * LDT];
  __shared__ __align__(16) __bf16 lB[128 * LDT];
  const int tid = threadIdx.x;
  const int lane = tid & 63;
  const int wid = tid >> 6;
  const int bn0 = blockIdx.x * 128;
  const int bm0 = blockIdx.y * 128;
  const int wm = (wid >> 1) * 64;
  const int wn = (wid & 1) * 64;
  const int lr = lane & 15;
  const int lk = (lane >> 4) * 8;

  f32x4 acc[4][4];
  #pragma unroll
  for (int i = 0; i < 4; ++i)
    #pragma unroll
    for (int j = 0; j < 4; ++j) acc[i][j] = (f32x4){0.f, 0.f, 0.f, 0.f};

  const int rs = tid >> 2;
  const int cs = (tid & 3) * 8;

  for (int k0 = 0; k0 < 1024; k0 += 32) {
    #pragma unroll
    for (int rr = 0; rr < 2; ++rr) {
      const int r = rs + rr * 64;
      const bf16x8 av = *(const bf16x8*)(A + (size_t)(bm0 + r) * 1024 + k0 + cs);
      const float* sb = W + (size_t)(bn0 + r) * 1024 + k0 + cs;
      float4 b0 = *(const float4*)sb;
      float4 b1 = *(const float4*)(sb + 4);
      *(bf16x8*)&lA[r * LDT + cs] = av;
      *(bf16x8*)&lB[r * LDT + cs] = cvt8(b0, b1);
    }
    __syncthreads();
    bf16x8 aF[4], bF[4];
    #pragma unroll
    for (int t = 0; t < 4; ++t) {
      aF[t] = *(const bf16x8*)&lA[(wm + t * 16 + lr) * LDT + lk];
      bF[t] = *(const bf16x8*)&lB[(wn + t * 16 + lr) * LDT + lk];
    }
    #pragma unroll
    for (int mt = 0; mt < 4; ++mt)
      #pragma unroll
      for (int nt = 0; nt < 4; ++nt)
        acc[mt][nt] = mfma16(aF[mt], bF[nt], acc[mt][nt]);
    __syncthreads();
  }

  const int col = lane & 15;
  const int rb = (lane >> 4) * 4;
  #pragma unroll
  for (int nt = 0; nt < 4; ++nt) {
    const int n = bn0 + wn + nt * 16 + col;
    const float bvv = bias[n];
    #pragma unroll
    for (int mt = 0; mt < 4; ++mt) {
      #pragma unroll
      for (int i = 0; i < 4; ++i) {
        const int m = bm0 + wm + mt * 16 + rb + i;
        O[(size_t)m * 1024 + n] = acc[mt][nt][i] + bvv;
      }
    }
  }
}

// ---------------------------------------------------------------------------
extern "C" void kernel_launch(void* const* d_in, const int* in_sizes, int n_in,
                              void* d_out, int out_size, void* d_ws, size_t ws_size,
                              hipStream_t stream)
{
  const float* query = (const float*)d_in[0];
  const float* key   = (const float*)d_in[1];
  const float* value = (const float*)d_in[2];
  const float* Wq = (const float*)d_in[3];
  const float* bq = (const float*)d_in[4];
  const float* Wk = (const float*)d_in[5];
  const float* bk = (const float*)d_in[6];
  const float* Wv = (const float*)d_in[7];
  const float* bv = (const float*)d_in[8];
  const float* Wo = (const float*)d_in[9];
  const float* bo = (const float*)d_in[10];

  float* out = (float*)d_out;
  float* amax_out = out + (size_t)8 * 1024 * 1024;  // out is [8,1024,1024] f32 first

  char* wsb = (char*)d_ws;
  __bf16* qp  = (__bf16*)wsb;                                 // 16MB
  __bf16* kp  = (__bf16*)(wsb + ((size_t)16 << 20));          // 16MB
  __bf16* vpT = (__bf16*)(wsb + ((size_t)32 << 20));          // 16MB [B][H][D][S]
  // rep: own slot if ws allows, else alias qp (safe: head h reads qp cols h*64
  // strictly before rep cols h*64 are written; rows are block-exclusive).
  __bf16* rep = (ws_size >= ((size_t)64 << 20)) ? (__bf16*)(wsb + ((size_t)48 << 20)) : qp;

  dim3 gG(8, 64);
  proj_gemm<0><<<gG, 256, 0, stream>>>(query, Wq, bq, qp, 0.125f);  // D^-0.5 folded
  proj_gemm<0><<<gG, 256, 0, stream>>>(key,   Wk, bk, kp, 1.0f);
  proj_gemm<1><<<gG, 256, 0, stream>>>(value, Wv, bv, vpT, 1.0f);
  attn_kernel<<<512, 256, 0, stream>>>(qp, kp, vpT, rep, amax_out);
  out_gemm<<<gG, 256, 0, stream>>>(rep, Wo, bo, out);
}

// Round 4
// 587.519 us; speedup vs baseline: 1.4147x; 1.4147x over previous
//
#include <hip/hip_runtime.h>

typedef __bf16 bf16x8 __attribute__((ext_vector_type(8)));
typedef __bf16 bf16x4 __attribute__((ext_vector_type(4)));
typedef float f32x4 __attribute__((ext_vector_type(4)));

__device__ __forceinline__ f32x4 mfma16(bf16x8 a, bf16x8 b, f32x4 c) {
  return __builtin_amdgcn_mfma_f32_16x16x32_bf16(a, b, c, 0, 0, 0);
}

__device__ __forceinline__ bf16x8 cvt8(float4 a, float4 b) {
  bf16x8 h;
  h[0] = (__bf16)a.x; h[1] = (__bf16)a.y; h[2] = (__bf16)a.z; h[3] = (__bf16)a.w;
  h[4] = (__bf16)b.x; h[5] = (__bf16)b.y; h[6] = (__bf16)b.z; h[7] = (__bf16)b.w;
  return h;
}

// ---------------------------------------------------------------------------
// Kernel 1: projection GEMM (NT): O[m][n] = (sum_k A[m][k]*W[n][k] + bias[n])*scale
// A: f32 [8192][1024], W: f32 [1024][1024] (row-major [n][k]) -> bf16 out.
// OUT_MODE 0: row-major [8192][1024].  OUT_MODE 1: vpT layout [B][H][D][S].
// ---------------------------------------------------------------------------
template<int OUT_MODE>
__global__ __launch_bounds__(256, 2)
void proj_gemm(const float* __restrict__ A, const float* __restrict__ W,
               const float* __restrict__ bias, __bf16* __restrict__ O, float scale)
{
  constexpr int LDT = 40;  // padded bf16 stride (80B rows) to break LDS bank conflicts
  __shared__ __align__(16) __bf16 lA[128 * LDT];
  __shared__ __align__(16) __bf16 lB[128 * LDT];
  const int tid = threadIdx.x;
  const int lane = tid & 63;
  const int wid = tid >> 6;
  const int bn0 = blockIdx.x * 128;
  const int bm0 = blockIdx.y * 128;
  const int wm = (wid >> 1) * 64;
  const int wn = (wid & 1) * 64;
  const int lr = lane & 15;
  const int lk = (lane >> 4) * 8;

  f32x4 acc[4][4];
  #pragma unroll
  for (int i = 0; i < 4; ++i)
    #pragma unroll
    for (int j = 0; j < 4; ++j) acc[i][j] = (f32x4){0.f, 0.f, 0.f, 0.f};

  const int rs = tid >> 2;        // 0..63
  const int cs = (tid & 3) * 8;   // 0,8,16,24

  for (int k0 = 0; k0 < 1024; k0 += 32) {
    #pragma unroll
    for (int rr = 0; rr < 2; ++rr) {
      const int r = rs + rr * 64;
      const float* sa = A + (size_t)(bm0 + r) * 1024 + k0 + cs;
      const float* sb = W + (size_t)(bn0 + r) * 1024 + k0 + cs;
      float4 a0 = *(const float4*)sa;
      float4 a1 = *(const float4*)(sa + 4);
      float4 b0 = *(const float4*)sb;
      float4 b1 = *(const float4*)(sb + 4);
      *(bf16x8*)&lA[r * LDT + cs] = cvt8(a0, a1);
      *(bf16x8*)&lB[r * LDT + cs] = cvt8(b0, b1);
    }
    __syncthreads();
    bf16x8 aF[4], bF[4];
    #pragma unroll
    for (int t = 0; t < 4; ++t) {
      aF[t] = *(const bf16x8*)&lA[(wm + t * 16 + lr) * LDT + lk];
      bF[t] = *(const bf16x8*)&lB[(wn + t * 16 + lr) * LDT + lk];
    }
    #pragma unroll
    for (int mt = 0; mt < 4; ++mt)
      #pragma unroll
      for (int nt = 0; nt < 4; ++nt)
        acc[mt][nt] = mfma16(aF[mt], bF[nt], acc[mt][nt]);
    __syncthreads();
  }

  const int col = lane & 15;
  const int rb = (lane >> 4) * 4;
  #pragma unroll
  for (int nt = 0; nt < 4; ++nt) {
    const int n = bn0 + wn + nt * 16 + col;
    const float bvv = bias[n];
    #pragma unroll
    for (int mt = 0; mt < 4; ++mt) {
      #pragma unroll
      for (int i = 0; i < 4; ++i) {
        const int m = bm0 + wm + mt * 16 + rb + i;
        const float v = (acc[mt][nt][i] + bvv) * scale;
        if constexpr (OUT_MODE == 0) {
          O[(size_t)m * 1024 + n] = (__bf16)v;
        } else {
          // vpT[b][h][d][s]: b=m>>10, s=m&1023, h=n>>6, d=n&63
          const int bb = m >> 10, s = m & 1023, hh = n >> 6, dd = n & 63;
          O[((size_t)((bb * 16 + hh) * 64 + dd)) * 1024 + s] = (__bf16)v;
        }
      }
    }
  }
}

// ---------------------------------------------------------------------------
// Kernel 2: attention, swapped-QK^T lane-local softmax, no P LDS round trip.
// Block = (b, 16 t-rows), 4 waves; wave w owns s-slice [w*256, w*256+256).
// mfma(K, Q) -> D[s][t]: lane holds t=lane&15, s=(lane>>4)*4+i per j-chunk,
// i.e. 64 s-values for ONE t-row => row softmax is in-register + 2 shfl_xor
// + tiny cross-wave LDS reduce. P feeds PV A-fragments directly (no shuffles,
// no P staging). Partial o combined across waves via 17-padded LDS tile.
// attn_max kept packed bf16 in regs, written coalesced at the end.
// NOTE: ALL loops touching p[] are FULLY unrolled — partial unroll puts p[]
// in scratch (963 MB of spill traffic in R3; rule #20).
// ---------------------------------------------------------------------------
__global__ __launch_bounds__(256, 3)
void attn_kernel(const __bf16* __restrict__ qp, const __bf16* __restrict__ kp,
                 const __bf16* __restrict__ vpT, __bf16* __restrict__ rep,
                 float* __restrict__ amax_out)
{
  __shared__ float redm[16 * 4];
  __shared__ float reds[16 * 4];
  __shared__ __align__(16) float ob[4 * 64 * 17];  // [wave][d][t] padded

  const int bid = blockIdx.x;
  const int b = bid & 7;          // same-b blocks -> same XCD (L2 reuse of kp/vpT)
  const int t0 = (bid >> 3) * 16;
  const int tid = threadIdx.x;
  const int lane = tid & 63;
  const int w = tid >> 6;         // wave owns s-slice [w*256, w*256+256)
  const int lr = lane & 15;
  const int g = lane >> 4;

  bf16x4 am4[16];                 // running max over heads, packed bf16
  #pragma unroll
  for (int j = 0; j < 16; ++j)
    #pragma unroll
    for (int i = 0; i < 4; ++i) am4[j][i] = (__bf16)0.f;

  const size_t qrow = (size_t)(b * 1024 + t0 + lr) * 1024;

  for (int h = 0; h < 16; ++h) {
    // ---- Q B-fragment (n = t = lr) ----
    const __bf16* qb = qp + qrow + h * 64 + g * 8;
    const bf16x8 bF0 = *(const bf16x8*)qb;
    const bf16x8 bF1 = *(const bf16x8*)(qb + 32);

    // ---- QK^T swapped: p[j] = D[s][t], s = w*256 + j*16 + g*4 + i, t = lr ----
    f32x4 p[16];
    #pragma unroll
    for (int j = 0; j < 16; ++j) {
      const int s0 = w * 256 + j * 16;
      const __bf16* kb = kp + (size_t)(b * 1024 + s0 + lr) * 1024 + h * 64 + g * 8;
      const bf16x8 aF0 = *(const bf16x8*)kb;
      const bf16x8 aF1 = *(const bf16x8*)(kb + 32);
      f32x4 d = {0.f, 0.f, 0.f, 0.f};
      d = mfma16(aF0, bF0, d);
      d = mfma16(aF1, bF1, d);
      p[j] = d;
    }

    // ---- row max: in-register (lane-local!) + 2 shfl + cross-wave LDS ----
    f32x4 m4 = p[0];
    #pragma unroll
    for (int j = 1; j < 16; ++j)
      #pragma unroll
      for (int i = 0; i < 4; ++i) m4[i] = fmaxf(m4[i], p[j][i]);
    float mm = fmaxf(fmaxf(m4[0], m4[1]), fmaxf(m4[2], m4[3]));
    mm = fmaxf(mm, __shfl_xor(mm, 16));
    mm = fmaxf(mm, __shfl_xor(mm, 32));
    if (lane < 16) redm[lr * 4 + w] = mm;
    __syncthreads();  // B1
    const f32x4 mv = *(const f32x4*)&redm[lr * 4];
    const float mfin = fmaxf(fmaxf(mv[0], mv[1]), fmaxf(mv[2], mv[3]));

    // ---- exp + sum (lane-local) ----
    f32x4 s4 = {0.f, 0.f, 0.f, 0.f};
    #pragma unroll
    for (int j = 0; j < 16; ++j) {
      #pragma unroll
      for (int i = 0; i < 4; ++i) {
        const float e = __expf(p[j][i] - mfin);
        p[j][i] = e;
        s4[i] += e;
      }
    }
    float ss = (s4[0] + s4[1]) + (s4[2] + s4[3]);
    ss += __shfl_xor(ss, 16);
    ss += __shfl_xor(ss, 32);
    if (lane < 16) reds[lr * 4 + w] = ss;
    __syncthreads();  // B2
    const f32x4 sv = *(const f32x4*)&reds[lr * 4];
    const float inv = 1.f / ((sv[0] + sv[1]) + (sv[2] + sv[3]));

    // ---- running attn_max (normalized), packed bf16 ----
    #pragma unroll
    for (int j = 0; j < 16; ++j) {
      #pragma unroll
      for (int i = 0; i < 4; ++i) {
        const float pn = p[j][i] * inv;
        const float o = (float)am4[j][i];
        am4[j][i] = (__bf16)fmaxf(o, pn);
      }
    }

    // ---- PV: A=P (m=t), B=V (n=d). D[t][d]: row t = g*4+i, col d = dc*16+lr.
    //      k-map: av[i]=p[2m][i] (s=m*32+g*4+i), av[4+i]=p[2m+1][i] (s=m*32+16+g*4+i)
    //      matches V loads at so=m*32+g*4 and so+16. Unnormalized. ----
    f32x4 po[4];
    #pragma unroll
    for (int dc = 0; dc < 4; ++dc) po[dc] = (f32x4){0.f, 0.f, 0.f, 0.f};
    const __bf16* vb0 = vpT + ((size_t)((b * 16 + h) * 64) + lr) * 1024 + w * 256;
    #pragma unroll
    for (int m = 0; m < 8; ++m) {
      bf16x8 av;
      #pragma unroll
      for (int i = 0; i < 4; ++i) {
        av[i] = (__bf16)p[2 * m][i];
        av[4 + i] = (__bf16)p[2 * m + 1][i];
      }
      const int so = m * 32 + g * 4;
      #pragma unroll
      for (int dc = 0; dc < 4; ++dc) {
        const __bf16* vb = vb0 + (size_t)(dc * 16) * 1024;
        const bf16x4 b0 = *(const bf16x4*)(vb + so);
        const bf16x4 b1 = *(const bf16x4*)(vb + so + 16);
        bf16x8 bv;
        #pragma unroll
        for (int i = 0; i < 4; ++i) { bv[i] = b0[i]; bv[4 + i] = b1[i]; }
        po[dc] = mfma16(av, bv, po[dc]);
      }
    }

    // ---- cross-wave o combine via LDS (ob[w][d][t], pad 17) ----
    #pragma unroll
    for (int dc = 0; dc < 4; ++dc)
      *(f32x4*)&ob[(w * 64 + dc * 16 + lr) * 17 + g * 4] = po[dc];
    __syncthreads();  // B3
    f32x4 fin = {0.f, 0.f, 0.f, 0.f};
    #pragma unroll
    for (int w2 = 0; w2 < 4; ++w2) {
      const f32x4 t4 = *(const f32x4*)&ob[(w2 * 64 + w * 16 + lr) * 17 + g * 4];
      #pragma unroll
      for (int i = 0; i < 4; ++i) fin[i] += t4[i];
    }
    // inv for rows t = g*4+i lives in lane lr' = g*4+i (same wave)
    #pragma unroll
    for (int i = 0; i < 4; ++i) {
      const float iv = __shfl(inv, g * 4 + i);
      rep[(size_t)(b * 1024 + t0 + g * 4 + i) * 1024 + h * 64 + w * 16 + lr] =
          (__bf16)(fin[i] * iv);
    }
  }

  // ---- write attn_max: lane covers t = lr, s = w*256 + j*16 + g*4 + i ----
  const size_t arow = (size_t)(b * 1024 + t0 + lr) * 1024;
  #pragma unroll
  for (int j = 0; j < 16; ++j) {
    f32x4 v;
    #pragma unroll
    for (int i = 0; i < 4; ++i) v[i] = (float)am4[j][i];
    *(f32x4*)&amax_out[arow + w * 256 + j * 16 + g * 4] = v;
  }
}

// ---------------------------------------------------------------------------
// Kernel 3: out projection: O[m][n] = sum_k rep[m][k]*Wo[n][k] + bo[n]  (f32 out)
// ---------------------------------------------------------------------------
__global__ __launch_bounds__(256, 2)
void out_gemm(const __bf16* __restrict__ A, const float* __restrict__ W,
              const float* __restrict__ bias, float* __restrict__ O)
{
  constexpr int LDT = 40;
  __shared__ __align__(16) __bf16 lA[128 * LDT];
  __shared__ __align__(16) __bf16 lB[128 * LDT];
  const int tid = threadIdx.x;
  const int lane = tid & 63;
  const int wid = tid >> 6;
  const int bn0 = blockIdx.x * 128;
  const int bm0 = blockIdx.y * 128;
  const int wm = (wid >> 1) * 64;
  const int wn = (wid & 1) * 64;
  const int lr = lane & 15;
  const int lk = (lane >> 4) * 8;

  f32x4 acc[4][4];
  #pragma unroll
  for (int i = 0; i < 4; ++i)
    #pragma unroll
    for (int j = 0; j < 4; ++j) acc[i][j] = (f32x4){0.f, 0.f, 0.f, 0.f};

  const int rs = tid >> 2;
  const int cs = (tid & 3) * 8;

  for (int k0 = 0; k0 < 1024; k0 += 32) {
    #pragma unroll
    for (int rr = 0; rr < 2; ++rr) {
      const int r = rs + rr * 64;
      const bf16x8 av = *(const bf16x8*)(A + (size_t)(bm0 + r) * 1024 + k0 + cs);
      const float* sb = W + (size_t)(bn0 + r) * 1024 + k0 + cs;
      float4 b0 = *(const float4*)sb;
      float4 b1 = *(const float4*)(sb + 4);
      *(bf16x8*)&lA[r * LDT + cs] = av;
      *(bf16x8*)&lB[r * LDT + cs] = cvt8(b0, b1);
    }
    __syncthreads();
    bf16x8 aF[4], bF[4];
    #pragma unroll
    for (int t = 0; t < 4; ++t) {
      aF[t] = *(const bf16x8*)&lA[(wm + t * 16 + lr) * LDT + lk];
      bF[t] = *(const bf16x8*)&lB[(wn + t * 16 + lr) * LDT + lk];
    }
    #pragma unroll
    for (int mt = 0; mt < 4; ++mt)
      #pragma unroll
      for (int nt = 0; nt < 4; ++nt)
        acc[mt][nt] = mfma16(aF[mt], bF[nt], acc[mt][nt]);
    __syncthreads();
  }

  const int col = lane & 15;
  const int rb = (lane >> 4) * 4;
  #pragma unroll
  for (int nt = 0; nt < 4; ++nt) {
    const int n = bn0 + wn + nt * 16 + col;
    const float bvv = bias[n];
    #pragma unroll
    for (int mt = 0; mt < 4; ++mt) {
      #pragma unroll
      for (int i = 0; i < 4; ++i) {
        const int m = bm0 + wm + mt * 16 + rb + i;
        O[(size_t)m * 1024 + n] = acc[mt][nt][i] + bvv;
      }
    }
  }
}

// ---------------------------------------------------------------------------
extern "C" void kernel_launch(void* const* d_in, const int* in_sizes, int n_in,
                              void* d_out, int out_size, void* d_ws, size_t ws_size,
                              hipStream_t stream)
{
  const float* query = (const float*)d_in[0];
  const float* key   = (const float*)d_in[1];
  const float* value = (const float*)d_in[2];
  const float* Wq = (const float*)d_in[3];
  const float* bq = (const float*)d_in[4];
  const float* Wk = (const float*)d_in[5];
  const float* bk = (const float*)d_in[6];
  const float* Wv = (const float*)d_in[7];
  const float* bv = (const float*)d_in[8];
  const float* Wo = (const float*)d_in[9];
  const float* bo = (const float*)d_in[10];

  float* out = (float*)d_out;
  float* amax_out = out + (size_t)8 * 1024 * 1024;  // out is [8,1024,1024] f32 first

  char* wsb = (char*)d_ws;
  __bf16* qp  = (__bf16*)wsb;                                 // 16MB
  __bf16* kp  = (__bf16*)(wsb + ((size_t)16 << 20));          // 16MB
  __bf16* vpT = (__bf16*)(wsb + ((size_t)32 << 20));          // 16MB [B][H][D][S]
  // rep: own slot if ws allows, else alias qp (safe: head h reads qp cols h*64
  // strictly before rep cols h*64 are written; rows are block-exclusive).
  __bf16* rep = (ws_size >= ((size_t)64 << 20)) ? (__bf16*)(wsb + ((size_t)48 << 20)) : qp;

  dim3 gG(8, 64);
  proj_gemm<0><<<gG, 256, 0, stream>>>(query, Wq, bq, qp, 0.125f);  // D^-0.5 folded
  proj_gemm<0><<<gG, 256, 0, stream>>>(key,   Wk, bk, kp, 1.0f);
  proj_gemm<1><<<gG, 256, 0, stream>>>(value, Wv, bv, vpT, 1.0f);
  attn_kernel<<<512, 256, 0, stream>>>(qp, kp, vpT, rep, amax_out);
  out_gemm<<<gG, 256, 0, stream>>>(rep, Wo, bo, out);
}

// Round 5
// 551.480 us; speedup vs baseline: 1.5072x; 1.0654x over previous
//
#include <hip/hip_runtime.h>

typedef __bf16 bf16x8 __attribute__((ext_vector_type(8)));
typedef __bf16 bf16x4 __attribute__((ext_vector_type(4)));
typedef float f32x4 __attribute__((ext_vector_type(4)));

__device__ __forceinline__ f32x4 mfma16(bf16x8 a, bf16x8 b, f32x4 c) {
  return __builtin_amdgcn_mfma_f32_16x16x32_bf16(a, b, c, 0, 0, 0);
}

__device__ __forceinline__ bf16x8 cvt8(float4 a, float4 b) {
  bf16x8 h;
  h[0] = (__bf16)a.x; h[1] = (__bf16)a.y; h[2] = (__bf16)a.z; h[3] = (__bf16)a.w;
  h[4] = (__bf16)b.x; h[5] = (__bf16)b.y; h[6] = (__bf16)b.z; h[7] = (__bf16)b.w;
  return h;
}

// ---------------------------------------------------------------------------
// Kernel 1: projection GEMM (NT): O[m][n] = (sum_k A[m][k]*W[n][k] + bias[n])*scale
// A: f32 [8192][1024], W: f32 [1024][1024] (row-major [n][k]) -> bf16 out.
// OUT_MODE 0: row-major [8192][1024].  OUT_MODE 1: vpT layout [B][H][D][S].
// ---------------------------------------------------------------------------
template<int OUT_MODE>
__global__ __launch_bounds__(256, 2)
void proj_gemm(const float* __restrict__ A, const float* __restrict__ W,
               const float* __restrict__ bias, __bf16* __restrict__ O, float scale)
{
  constexpr int LDT = 40;  // padded bf16 stride (80B rows) to break LDS bank conflicts
  __shared__ __align__(16) __bf16 lA[128 * LDT];
  __shared__ __align__(16) __bf16 lB[128 * LDT];
  const int tid = threadIdx.x;
  const int lane = tid & 63;
  const int wid = tid >> 6;
  const int bn0 = blockIdx.x * 128;
  const int bm0 = blockIdx.y * 128;
  const int wm = (wid >> 1) * 64;
  const int wn = (wid & 1) * 64;
  const int lr = lane & 15;
  const int lk = (lane >> 4) * 8;

  f32x4 acc[4][4];
  #pragma unroll
  for (int i = 0; i < 4; ++i)
    #pragma unroll
    for (int j = 0; j < 4; ++j) acc[i][j] = (f32x4){0.f, 0.f, 0.f, 0.f};

  const int rs = tid >> 2;        // 0..63
  const int cs = (tid & 3) * 8;   // 0,8,16,24

  for (int k0 = 0; k0 < 1024; k0 += 32) {
    #pragma unroll
    for (int rr = 0; rr < 2; ++rr) {
      const int r = rs + rr * 64;
      const float* sa = A + (size_t)(bm0 + r) * 1024 + k0 + cs;
      const float* sb = W + (size_t)(bn0 + r) * 1024 + k0 + cs;
      float4 a0 = *(const float4*)sa;
      float4 a1 = *(const float4*)(sa + 4);
      float4 b0 = *(const float4*)sb;
      float4 b1 = *(const float4*)(sb + 4);
      *(bf16x8*)&lA[r * LDT + cs] = cvt8(a0, a1);
      *(bf16x8*)&lB[r * LDT + cs] = cvt8(b0, b1);
    }
    __syncthreads();
    bf16x8 aF[4], bF[4];
    #pragma unroll
    for (int t = 0; t < 4; ++t) {
      aF[t] = *(const bf16x8*)&lA[(wm + t * 16 + lr) * LDT + lk];
      bF[t] = *(const bf16x8*)&lB[(wn + t * 16 + lr) * LDT + lk];
    }
    #pragma unroll
    for (int mt = 0; mt < 4; ++mt)
      #pragma unroll
      for (int nt = 0; nt < 4; ++nt)
        acc[mt][nt] = mfma16(aF[mt], bF[nt], acc[mt][nt]);
    __syncthreads();
  }

  const int col = lane & 15;
  const int rb = (lane >> 4) * 4;
  #pragma unroll
  for (int nt = 0; nt < 4; ++nt) {
    const int n = bn0 + wn + nt * 16 + col;
    const float bvv = bias[n];
    #pragma unroll
    for (int mt = 0; mt < 4; ++mt) {
      #pragma unroll
      for (int i = 0; i < 4; ++i) {
        const int m = bm0 + wm + mt * 16 + rb + i;
        const float v = (acc[mt][nt][i] + bvv) * scale;
        if constexpr (OUT_MODE == 0) {
          O[(size_t)m * 1024 + n] = (__bf16)v;
        } else {
          // vpT[b][h][d][s]: b=m>>10, s=m&1023, h=n>>6, d=n&63
          const int bb = m >> 10, s = m & 1023, hh = n >> 6, dd = n & 63;
          O[((size_t)((bb * 16 + hh) * 64 + dd)) * 1024 + s] = (__bf16)v;
        }
      }
    }
  }
}

// ---------------------------------------------------------------------------
// Kernel 2: attention, swapped-QK^T lane-local softmax, no P LDS round trip.
// Block = (b, 16 t-rows), 4 waves; wave w owns s-slice [w*256, w*256+256).
// mfma(K, Q) -> D[s][t]: lane holds t=lane&15, s=(lane>>4)*4+i per j-chunk,
// i.e. 64 s-values for ONE t-row => row softmax is in-register + 2 shfl_xor
// + tiny cross-wave LDS reduce. P feeds PV A-fragments directly (no shuffles,
// no P staging). Partial o combined across waves via 17-padded LDS tile.
// attn_max kept packed bf16 in regs, written coalesced at the end.
// NOTE: launch_bounds must allow ~200+ VGPRs: R4 proved a 170 cap makes the
// allocator spill (VGPR_Count=84, +76MB scratch writes). Occupancy is
// grid-limited at 2 blocks/CU anyway, so (256,2) costs nothing.
// ---------------------------------------------------------------------------
__global__ __launch_bounds__(256, 2)
void attn_kernel(const __bf16* __restrict__ qp, const __bf16* __restrict__ kp,
                 const __bf16* __restrict__ vpT, __bf16* __restrict__ rep,
                 float* __restrict__ amax_out)
{
  __shared__ float redm[16 * 4];
  __shared__ float reds[16 * 4];
  __shared__ __align__(16) float ob[4 * 64 * 17];  // [wave][d][t] padded

  const int bid = blockIdx.x;
  const int b = bid & 7;          // same-b blocks -> same XCD (L2 reuse of kp/vpT)
  const int t0 = (bid >> 3) * 16;
  const int tid = threadIdx.x;
  const int lane = tid & 63;
  const int w = tid >> 6;         // wave owns s-slice [w*256, w*256+256)
  const int lr = lane & 15;
  const int g = lane >> 4;

  bf16x4 am4[16];                 // running max over heads, packed bf16
  #pragma unroll
  for (int j = 0; j < 16; ++j)
    #pragma unroll
    for (int i = 0; i < 4; ++i) am4[j][i] = (__bf16)0.f;

  const size_t qrow = (size_t)(b * 1024 + t0 + lr) * 1024;

  for (int h = 0; h < 16; ++h) {
    // ---- Q B-fragment (n = t = lr) ----
    const __bf16* qb = qp + qrow + h * 64 + g * 8;
    const bf16x8 bF0 = *(const bf16x8*)qb;
    const bf16x8 bF1 = *(const bf16x8*)(qb + 32);

    // ---- QK^T swapped: p[j] = D[s][t], s = w*256 + j*16 + g*4 + i, t = lr ----
    f32x4 p[16];
    #pragma unroll
    for (int j = 0; j < 16; ++j) {
      const int s0 = w * 256 + j * 16;
      const __bf16* kb = kp + (size_t)(b * 1024 + s0 + lr) * 1024 + h * 64 + g * 8;
      const bf16x8 aF0 = *(const bf16x8*)kb;
      const bf16x8 aF1 = *(const bf16x8*)(kb + 32);
      f32x4 d = {0.f, 0.f, 0.f, 0.f};
      d = mfma16(aF0, bF0, d);
      d = mfma16(aF1, bF1, d);
      p[j] = d;
    }

    // ---- row max: in-register (lane-local!) + 2 shfl + cross-wave LDS ----
    f32x4 m4 = p[0];
    #pragma unroll
    for (int j = 1; j < 16; ++j)
      #pragma unroll
      for (int i = 0; i < 4; ++i) m4[i] = fmaxf(m4[i], p[j][i]);
    float mm = fmaxf(fmaxf(m4[0], m4[1]), fmaxf(m4[2], m4[3]));
    mm = fmaxf(mm, __shfl_xor(mm, 16));
    mm = fmaxf(mm, __shfl_xor(mm, 32));
    if (lane < 16) redm[lr * 4 + w] = mm;
    __syncthreads();  // B1
    const f32x4 mv = *(const f32x4*)&redm[lr * 4];
    const float mfin = fmaxf(fmaxf(mv[0], mv[1]), fmaxf(mv[2], mv[3]));

    // ---- exp + sum (lane-local) ----
    f32x4 s4 = {0.f, 0.f, 0.f, 0.f};
    #pragma unroll
    for (int j = 0; j < 16; ++j) {
      #pragma unroll
      for (int i = 0; i < 4; ++i) {
        const float e = __expf(p[j][i] - mfin);
        p[j][i] = e;
        s4[i] += e;
      }
    }
    float ss = (s4[0] + s4[1]) + (s4[2] + s4[3]);
    ss += __shfl_xor(ss, 16);
    ss += __shfl_xor(ss, 32);
    if (lane < 16) reds[lr * 4 + w] = ss;
    __syncthreads();  // B2
    const f32x4 sv = *(const f32x4*)&reds[lr * 4];
    const float inv = 1.f / ((sv[0] + sv[1]) + (sv[2] + sv[3]));

    // ---- running attn_max (normalized), packed bf16 ----
    #pragma unroll
    for (int j = 0; j < 16; ++j) {
      #pragma unroll
      for (int i = 0; i < 4; ++i) {
        const float pn = p[j][i] * inv;
        const float o = (float)am4[j][i];
        am4[j][i] = (__bf16)fmaxf(o, pn);
      }
    }

    // ---- PV: A=P (m=t), B=V (n=d). D[t][d]: row t = g*4+i, col d = dc*16+lr.
    //      k-map: av[i]=p[2m][i] (s=m*32+g*4+i), av[4+i]=p[2m+1][i] (s=m*32+16+g*4+i)
    //      matches V loads at so=m*32+g*4 and so+16. Unnormalized. ----
    f32x4 po[4];
    #pragma unroll
    for (int dc = 0; dc < 4; ++dc) po[dc] = (f32x4){0.f, 0.f, 0.f, 0.f};
    const __bf16* vb0 = vpT + ((size_t)((b * 16 + h) * 64) + lr) * 1024 + w * 256;
    #pragma unroll
    for (int m = 0; m < 8; ++m) {
      bf16x8 av;
      #pragma unroll
      for (int i = 0; i < 4; ++i) {
        av[i] = (__bf16)p[2 * m][i];
        av[4 + i] = (__bf16)p[2 * m + 1][i];
      }
      const int so = m * 32 + g * 4;
      #pragma unroll
      for (int dc = 0; dc < 4; ++dc) {
        const __bf16* vb = vb0 + (size_t)(dc * 16) * 1024;
        const bf16x4 b0 = *(const bf16x4*)(vb + so);
        const bf16x4 b1 = *(const bf16x4*)(vb + so + 16);
        bf16x8 bv;
        #pragma unroll
        for (int i = 0; i < 4; ++i) { bv[i] = b0[i]; bv[4 + i] = b1[i]; }
        po[dc] = mfma16(av, bv, po[dc]);
      }
    }

    // ---- cross-wave o combine via LDS (ob[w][d][t], pad 17) ----
    #pragma unroll
    for (int dc = 0; dc < 4; ++dc)
      *(f32x4*)&ob[(w * 64 + dc * 16 + lr) * 17 + g * 4] = po[dc];
    __syncthreads();  // B3
    f32x4 fin = {0.f, 0.f, 0.f, 0.f};
    #pragma unroll
    for (int w2 = 0; w2 < 4; ++w2) {
      const f32x4 t4 = *(const f32x4*)&ob[(w2 * 64 + w * 16 + lr) * 17 + g * 4];
      #pragma unroll
      for (int i = 0; i < 4; ++i) fin[i] += t4[i];
    }
    // inv for rows t = g*4+i lives in lane lr' = g*4+i (same wave)
    #pragma unroll
    for (int i = 0; i < 4; ++i) {
      const float iv = __shfl(inv, g * 4 + i);
      rep[(size_t)(b * 1024 + t0 + g * 4 + i) * 1024 + h * 64 + w * 16 + lr] =
          (__bf16)(fin[i] * iv);
    }
  }

  // ---- write attn_max: lane covers t = lr, s = w*256 + j*16 + g*4 + i ----
  const size_t arow = (size_t)(b * 1024 + t0 + lr) * 1024;
  #pragma unroll
  for (int j = 0; j < 16; ++j) {
    f32x4 v;
    #pragma unroll
    for (int i = 0; i < 4; ++i) v[i] = (float)am4[j][i];
    *(f32x4*)&amax_out[arow + w * 256 + j * 16 + g * 4] = v;
  }
}

// ---------------------------------------------------------------------------
// Kernel 3: out projection: O[m][n] = sum_k rep[m][k]*Wo[n][k] + bo[n]  (f32 out)
// ---------------------------------------------------------------------------
__global__ __launch_bounds__(256, 2)
void out_gemm(const __bf16* __restrict__ A, const float* __restrict__ W,
              const float* __restrict__ bias, float* __restrict__ O)
{
  constexpr int LDT = 40;
  __shared__ __align__(16) __bf16 lA[128 * LDT];
  __shared__ __align__(16) __bf16 lB[128 * LDT];
  const int tid = threadIdx.x;
  const int lane = tid & 63;
  const int wid = tid >> 6;
  const int bn0 = blockIdx.x * 128;
  const int bm0 = blockIdx.y * 128;
  const int wm = (wid >> 1) * 64;
  const int wn = (wid & 1) * 64;
  const int lr = lane & 15;
  const int lk = (lane >> 4) * 8;

  f32x4 acc[4][4];
  #pragma unroll
  for (int i = 0; i < 4; ++i)
    #pragma unroll
    for (int j = 0; j < 4; ++j) acc[i][j] = (f32x4){0.f, 0.f, 0.f, 0.f};

  const int rs = tid >> 2;
  const int cs = (tid & 3) * 8;

  for (int k0 = 0; k0 < 1024; k0 += 32) {
    #pragma unroll
    for (int rr = 0; rr < 2; ++rr) {
      const int r = rs + rr * 64;
      const bf16x8 av = *(const bf16x8*)(A + (size_t)(bm0 + r) * 1024 + k0 + cs);
      const float* sb = W + (size_t)(bn0 + r) * 1024 + k0 + cs;
      float4 b0 = *(const float4*)sb;
      float4 b1 = *(const float4*)(sb + 4);
      *(bf16x8*)&lA[r * LDT + cs] = av;
      *(bf16x8*)&lB[r * LDT + cs] = cvt8(b0, b1);
    }
    __syncthreads();
    bf16x8 aF[4], bF[4];
    #pragma unroll
    for (int t = 0; t < 4; ++t) {
      aF[t] = *(const bf16x8*)&lA[(wm + t * 16 + lr) * LDT + lk];
      bF[t] = *(const bf16x8*)&lB[(wn + t * 16 + lr) * LDT + lk];
    }
    #pragma unroll
    for (int mt = 0; mt < 4; ++mt)
      #pragma unroll
      for (int nt = 0; nt < 4; ++nt)
        acc[mt][nt] = mfma16(aF[mt], bF[nt], acc[mt][nt]);
    __syncthreads();
  }

  const int col = lane & 15;
  const int rb = (lane >> 4) * 4;
  #pragma unroll
  for (int nt = 0; nt < 4; ++nt) {
    const int n = bn0 + wn + nt * 16 + col;
    const float bvv = bias[n];
    #pragma unroll
    for (int mt = 0; mt < 4; ++mt) {
      #pragma unroll
      for (int i = 0; i < 4; ++i) {
        const int m = bm0 + wm + mt * 16 + rb + i;
        O[(size_t)m * 1024 + n] = acc[mt][nt][i] + bvv;
      }
    }
  }
}

// ---------------------------------------------------------------------------
extern "C" void kernel_launch(void* const* d_in, const int* in_sizes, int n_in,
                              void* d_out, int out_size, void* d_ws, size_t ws_size,
                              hipStream_t stream)
{
  const float* query = (const float*)d_in[0];
  const float* key   = (const float*)d_in[1];
  const float* value = (const float*)d_in[2];
  const float* Wq = (const float*)d_in[3];
  const float* bq = (const float*)d_in[4];
  const float* Wk = (const float*)d_in[5];
  const float* bk = (const float*)d_in[6];
  const float* Wv = (const float*)d_in[7];
  const float* bv = (const float*)d_in[8];
  const float* Wo = (const float*)d_in[9];
  const float* bo = (const float*)d_in[10];

  float* out = (float*)d_out;
  float* amax_out = out + (size_t)8 * 1024 * 1024;  // out is [8,1024,1024] f32 first

  char* wsb = (char*)d_ws;
  __bf16* qp  = (__bf16*)wsb;                                 // 16MB
  __bf16* kp  = (__bf16*)(wsb + ((size_t)16 << 20));          // 16MB
  __bf16* vpT = (__bf16*)(wsb + ((size_t)32 << 20));          // 16MB [B][H][D][S]
  // rep: own slot if ws allows, else alias qp (safe: head h reads qp cols h*64
  // strictly before rep cols h*64 are written; rows are block-exclusive).
  __bf16* rep = (ws_size >= ((size_t)64 << 20)) ? (__bf16*)(wsb + ((size_t)48 << 20)) : qp;

  dim3 gG(8, 64);
  proj_gemm<0><<<gG, 256, 0, stream>>>(query, Wq, bq, qp, 0.125f);  // D^-0.5 folded
  proj_gemm<0><<<gG, 256, 0, stream>>>(key,   Wk, bk, kp, 1.0f);
  proj_gemm<1><<<gG, 256, 0, stream>>>(value, Wv, bv, vpT, 1.0f);
  attn_kernel<<<512, 256, 0, stream>>>(qp, kp, vpT, rep, amax_out);
  out_gemm<<<gG, 256, 0, stream>>>(rep, Wo, bo, out);
}

// Round 6
// 421.966 us; speedup vs baseline: 1.9697x; 1.3069x over previous
//
#include <hip/hip_runtime.h>

typedef __bf16 bf16x8 __attribute__((ext_vector_type(8)));
typedef __bf16 bf16x4 __attribute__((ext_vector_type(4)));
typedef float f32x4 __attribute__((ext_vector_type(4)));

__device__ __forceinline__ f32x4 mfma16(bf16x8 a, bf16x8 b, f32x4 c) {
  return __builtin_amdgcn_mfma_f32_16x16x32_bf16(a, b, c, 0, 0, 0);
}

__device__ __forceinline__ bf16x8 cvt8(float4 a, float4 b) {
  bf16x8 h;
  h[0] = (__bf16)a.x; h[1] = (__bf16)a.y; h[2] = (__bf16)a.z; h[3] = (__bf16)a.w;
  h[4] = (__bf16)b.x; h[5] = (__bf16)b.y; h[6] = (__bf16)b.z; h[7] = (__bf16)b.w;
  return h;
}

// ---------------------------------------------------------------------------
// Kernel 1: projection GEMM (NT): O[m][n] = (sum_k A[m][k]*W[n][k] + bias[n])*scale
// A: f32 [8192][1024], W: f32 [1024][1024] (row-major [n][k]) -> bf16 out.
// OUT_MODE 0: row-major [8192][1024].
// OUT_MODE 1: vpT layout [B][H][D][S'] with S interleaved within 32-blocks:
//   low5 = 4g+i (+16 if hi) -> 8g+4*hi+i, so the PV B-fragment (slots
//   {32m+4g+i} U {32m+16+4g+i}) is one contiguous 16B read.
// ---------------------------------------------------------------------------
template<int OUT_MODE>
__global__ __launch_bounds__(256, 2)
void proj_gemm(const float* __restrict__ A, const float* __restrict__ W,
               const float* __restrict__ bias, __bf16* __restrict__ O, float scale)
{
  constexpr int LDT = 40;  // padded bf16 stride (80B rows) to break LDS bank conflicts
  __shared__ __align__(16) __bf16 lA[128 * LDT];
  __shared__ __align__(16) __bf16 lB[128 * LDT];
  const int tid = threadIdx.x;
  const int lane = tid & 63;
  const int wid = tid >> 6;
  const int bn0 = blockIdx.x * 128;
  const int bm0 = blockIdx.y * 128;
  const int wm = (wid >> 1) * 64;
  const int wn = (wid & 1) * 64;
  const int lr = lane & 15;
  const int lk = (lane >> 4) * 8;

  f32x4 acc[4][4];
  #pragma unroll
  for (int i = 0; i < 4; ++i)
    #pragma unroll
    for (int j = 0; j < 4; ++j) acc[i][j] = (f32x4){0.f, 0.f, 0.f, 0.f};

  const int rs = tid >> 2;        // 0..63
  const int cs = (tid & 3) * 8;   // 0,8,16,24

  for (int k0 = 0; k0 < 1024; k0 += 32) {
    #pragma unroll
    for (int rr = 0; rr < 2; ++rr) {
      const int r = rs + rr * 64;
      const float* sa = A + (size_t)(bm0 + r) * 1024 + k0 + cs;
      const float* sb = W + (size_t)(bn0 + r) * 1024 + k0 + cs;
      float4 a0 = *(const float4*)sa;
      float4 a1 = *(const float4*)(sa + 4);
      float4 b0 = *(const float4*)sb;
      float4 b1 = *(const float4*)(sb + 4);
      *(bf16x8*)&lA[r * LDT + cs] = cvt8(a0, a1);
      *(bf16x8*)&lB[r * LDT + cs] = cvt8(b0, b1);
    }
    __syncthreads();
    bf16x8 aF[4], bF[4];
    #pragma unroll
    for (int t = 0; t < 4; ++t) {
      aF[t] = *(const bf16x8*)&lA[(wm + t * 16 + lr) * LDT + lk];
      bF[t] = *(const bf16x8*)&lB[(wn + t * 16 + lr) * LDT + lk];
    }
    #pragma unroll
    for (int mt = 0; mt < 4; ++mt)
      #pragma unroll
      for (int nt = 0; nt < 4; ++nt)
        acc[mt][nt] = mfma16(aF[mt], bF[nt], acc[mt][nt]);
    __syncthreads();
  }

  const int col = lane & 15;
  const int rb = (lane >> 4) * 4;
  #pragma unroll
  for (int nt = 0; nt < 4; ++nt) {
    const int n = bn0 + wn + nt * 16 + col;
    const float bvv = bias[n];
    #pragma unroll
    for (int mt = 0; mt < 4; ++mt) {
      #pragma unroll
      for (int i = 0; i < 4; ++i) {
        const int m = bm0 + wm + mt * 16 + rb + i;
        const float v = (acc[mt][nt][i] + bvv) * scale;
        if constexpr (OUT_MODE == 0) {
          O[(size_t)m * 1024 + n] = (__bf16)v;
        } else {
          // vpT[b][h][d][s']: b=m>>10, s=m&1023, h=n>>6, d=n&63
          const int bb = m >> 10, s = m & 1023, hh = n >> 6, dd = n & 63;
          const int low = s & 31;
          const int si = (s & ~31) | (((low >> 2) & 3) << 3) |
                         (((low >> 4) & 1) << 2) | (low & 3);
          O[((size_t)((bb * 16 + hh) * 64 + dd)) * 1024 + si] = (__bf16)v;
        }
      }
    }
  }
}

// ---------------------------------------------------------------------------
// Kernel 2: attention. 512 threads = 8 waves; wave w owns s in [w*128,w*128+128).
// Swapped QK^T (mfma(K,Q) -> D[s][t], t=lane&15, s=(lane>>4)*4+i): lane holds
// its t-row's 32 s-values -> softmax lane-local. Local-max variant: exp vs the
// wave's own max immediately, ONE barrier publishes (mw,sw); global rescale
// fw=exp(mw-m) is folded into the P->bf16 pack. P never touches LDS; V read as
// contiguous 16B thanks to interleaved vpT. Cross-wave PV combine via
// double-buffered ob -> 2 barriers/head total.
// __launch_bounds__(512,4): VGPR cap 128 -> 2 blocks/CU (16 waves/CU).
// Tripwire: if VGPR_Count ~85 + WRITE_SIZE >> 49MB, the cap spilled (rule R4).
// ---------------------------------------------------------------------------
__global__ __launch_bounds__(512, 4)
void attn_kernel(const __bf16* __restrict__ qp, const __bf16* __restrict__ kp,
                 const __bf16* __restrict__ vpT, __bf16* __restrict__ rep,
                 float* __restrict__ amax_out)
{
  __shared__ float2 red[16][8];                    // (mw, sw) per t-row per wave
  __shared__ float invb[16];
  __shared__ __align__(16) float ob[2][8 * 64 * 17];  // [buf][wave*64+d][t] padded

  const int bid = blockIdx.x;
  const int b = bid & 7;          // same-b blocks -> same XCD (L2 reuse of kp/vpT)
  const int t0 = (bid >> 3) * 16;
  const int tid = threadIdx.x;
  const int lane = tid & 63;
  const int w = tid >> 6;         // 0..7
  const int lr = lane & 15;
  const int g = lane >> 4;

  bf16x4 am4[8];                  // running max over heads, packed bf16
  #pragma unroll
  for (int j = 0; j < 8; ++j)
    #pragma unroll
    for (int i = 0; i < 4; ++i) am4[j][i] = (__bf16)0.f;

  const size_t qrow = (size_t)(b * 1024 + t0 + lr) * 1024;
  const int et = tid >> 5;        // epilogue row 0..15
  const int ed = tid & 31;        // epilogue col 0..31

  for (int h = 0; h < 16; ++h) {
    // ---- Q B-fragment (n = t = lr) ----
    const __bf16* qb = qp + qrow + h * 64 + g * 8;
    const bf16x8 bF0 = *(const bf16x8*)qb;
    const bf16x8 bF1 = *(const bf16x8*)(qb + 32);

    // ---- QK^T swapped: p[j] = D[s][t], s = w*128 + j*16 + g*4 + i, t = lr ----
    f32x4 p[8];
    #pragma unroll
    for (int j = 0; j < 8; ++j) {
      const int s0 = w * 128 + j * 16;
      const __bf16* kb = kp + (size_t)(b * 1024 + s0 + lr) * 1024 + h * 64 + g * 8;
      const bf16x8 aF0 = *(const bf16x8*)kb;
      const bf16x8 aF1 = *(const bf16x8*)(kb + 32);
      f32x4 d = {0.f, 0.f, 0.f, 0.f};
      d = mfma16(aF0, bF0, d);
      d = mfma16(aF1, bF1, d);
      p[j] = d;
    }

    // ---- wave-local max over this wave's 128 s (lane-local + 2 shfl) ----
    f32x4 m4 = p[0];
    #pragma unroll
    for (int j = 1; j < 8; ++j)
      #pragma unroll
      for (int i = 0; i < 4; ++i) m4[i] = fmaxf(m4[i], p[j][i]);
    float mm = fmaxf(fmaxf(m4[0], m4[1]), fmaxf(m4[2], m4[3]));
    mm = fmaxf(mm, __shfl_xor(mm, 16));
    mm = fmaxf(mm, __shfl_xor(mm, 32));

    // ---- exp vs local max + local sum (no barrier needed yet) ----
    f32x4 s4 = {0.f, 0.f, 0.f, 0.f};
    #pragma unroll
    for (int j = 0; j < 8; ++j) {
      #pragma unroll
      for (int i = 0; i < 4; ++i) {
        const float e = __expf(p[j][i] - mm);
        p[j][i] = e;
        s4[i] += e;
      }
    }
    float ss = (s4[0] + s4[1]) + (s4[2] + s4[3]);
    ss += __shfl_xor(ss, 16);
    ss += __shfl_xor(ss, 32);
    if (lane < 16) red[lr][w] = make_float2(mm, ss);
    __syncthreads();  // B1: publish (mw, sw)

    // ---- global max / sum / rescale ----
    float m = red[lr][0].x;
    #pragma unroll
    for (int k = 1; k < 8; ++k) m = fmaxf(m, red[lr][k].x);
    float sum = 0.f;
    #pragma unroll
    for (int k = 0; k < 8; ++k) sum += red[lr][k].y * __expf(red[lr][k].x - m);
    const float fw = __expf(mm - m);      // this wave's rescale to global max
    const float inv = 1.f / sum;
    if (w == 0 && lane < 16) invb[lr] = inv;
    const float c = fw * inv;

    // ---- running attn_max (normalized), packed bf16 ----
    #pragma unroll
    for (int j = 0; j < 8; ++j) {
      #pragma unroll
      for (int i = 0; i < 4; ++i) {
        const float pn = p[j][i] * c;
        const float o = (float)am4[j][i];
        am4[j][i] = (__bf16)fmaxf(o, pn);
      }
    }

    // ---- PV: A=P*fw (row t), B=V (col d). D[t][d]: t=g*4+i, d=dc*16+lr.
    //      k-map: av[i]=p[2m2][i]*fw (s=m2*32+4g+i), av[4+i]=p[2m2+1][i]*fw
    //      (s=m2*32+16+4g+i); interleaved vpT puts both halves at
    //      [d][m2*32+8g .. +7] -> single 16B load. ----
    f32x4 po[4];
    #pragma unroll
    for (int dc = 0; dc < 4; ++dc) po[dc] = (f32x4){0.f, 0.f, 0.f, 0.f};
    const __bf16* vb0 = vpT + ((size_t)((b * 16 + h) * 64) + lr) * 1024 + w * 128;
    #pragma unroll
    for (int m2 = 0; m2 < 4; ++m2) {
      bf16x8 av;
      #pragma unroll
      for (int i = 0; i < 4; ++i) {
        av[i] = (__bf16)(p[2 * m2][i] * fw);
        av[4 + i] = (__bf16)(p[2 * m2 + 1][i] * fw);
      }
      const int so = m2 * 32 + g * 8;
      #pragma unroll
      for (int dc = 0; dc < 4; ++dc) {
        const bf16x8 bv = *(const bf16x8*)(vb0 + (size_t)(dc * 16) * 1024 + so);
        po[dc] = mfma16(av, bv, po[dc]);
      }
    }

    // ---- cross-wave combine via double-buffered ob ----
    float* obh = ob[h & 1];
    #pragma unroll
    for (int dc = 0; dc < 4; ++dc)
      *(f32x4*)&obh[(w * 64 + dc * 16 + lr) * 17 + g * 4] = po[dc];
    __syncthreads();  // B2

    // ---- epilogue: thread (et=t, ed=d & d+32) sums 8 waves, writes rep ----
    float a0 = 0.f, a1 = 0.f;
    #pragma unroll
    for (int w2 = 0; w2 < 8; ++w2) {
      a0 += obh[(w2 * 64 + ed) * 17 + et];
      a1 += obh[(w2 * 64 + 32 + ed) * 17 + et];
    }
    const float ivv = invb[et];
    __bf16* rrow = rep + (size_t)(b * 1024 + t0 + et) * 1024 + h * 64;
    rrow[ed] = (__bf16)(a0 * ivv);
    rrow[32 + ed] = (__bf16)(a1 * ivv);
    // no 3rd barrier: ob is double-buffered; red/invb for h+1 are written only
    // after B1_{h+1}, which requires every wave to have finished this epilogue.
  }

  // ---- write attn_max: lane covers t = lr, s = w*128 + j*16 + g*4 + i ----
  const size_t arow = (size_t)(b * 1024 + t0 + lr) * 1024;
  #pragma unroll
  for (int j = 0; j < 8; ++j) {
    f32x4 v;
    #pragma unroll
    for (int i = 0; i < 4; ++i) v[i] = (float)am4[j][i];
    *(f32x4*)&amax_out[arow + w * 128 + j * 16 + g * 4] = v;
  }
}

// ---------------------------------------------------------------------------
// Kernel 3: out projection: O[m][n] = sum_k rep[m][k]*Wo[n][k] + bo[n]  (f32 out)
// ---------------------------------------------------------------------------
__global__ __launch_bounds__(256, 2)
void out_gemm(const __bf16* __restrict__ A, const float* __restrict__ W,
              const float* __restrict__ bias, float* __restrict__ O)
{
  constexpr int LDT = 40;
  __shared__ __align__(16) __bf16 lA[128 * LDT];
  __shared__ __align__(16) __bf16 lB[128 * LDT];
  const int tid = threadIdx.x;
  const int lane = tid & 63;
  const int wid = tid >> 6;
  const int bn0 = blockIdx.x * 128;
  const int bm0 = blockIdx.y * 128;
  const int wm = (wid >> 1) * 64;
  const int wn = (wid & 1) * 64;
  const int lr = lane & 15;
  const int lk = (lane >> 4) * 8;

  f32x4 acc[4][4];
  #pragma unroll
  for (int i = 0; i < 4; ++i)
    #pragma unroll
    for (int j = 0; j < 4; ++j) acc[i][j] = (f32x4){0.f, 0.f, 0.f, 0.f};

  const int rs = tid >> 2;
  const int cs = (tid & 3) * 8;

  for (int k0 = 0; k0 < 1024; k0 += 32) {
    #pragma unroll
    for (int rr = 0; rr < 2; ++rr) {
      const int r = rs + rr * 64;
      const bf16x8 av = *(const bf16x8*)(A + (size_t)(bm0 + r) * 1024 + k0 + cs);
      const float* sb = W + (size_t)(bn0 + r) * 1024 + k0 + cs;
      float4 b0 = *(const float4*)sb;
      float4 b1 = *(const float4*)(sb + 4);
      *(bf16x8*)&lA[r * LDT + cs] = av;
      *(bf16x8*)&lB[r * LDT + cs] = cvt8(b0, b1);
    }
    __syncthreads();
    bf16x8 aF[4], bF[4];
    #pragma unroll
    for (int t = 0; t < 4; ++t) {
      aF[t] = *(const bf16x8*)&lA[(wm + t * 16 + lr) * LDT + lk];
      bF[t] = *(const bf16x8*)&lB[(wn + t * 16 + lr) * LDT + lk];
    }
    #pragma unroll
    for (int mt = 0; mt < 4; ++mt)
      #pragma unroll
      for (int nt = 0; nt < 4; ++nt)
        acc[mt][nt] = mfma16(aF[mt], bF[nt], acc[mt][nt]);
    __syncthreads();
  }

  const int col = lane & 15;
  const int rb = (lane >> 4) * 4;
  #pragma unroll
  for (int nt = 0; nt < 4; ++nt) {
    const int n = bn0 + wn + nt * 16 + col;
    const float bvv = bias[n];
    #pragma unroll
    for (int mt = 0; mt < 4; ++mt) {
      #pragma unroll
      for (int i = 0; i < 4; ++i) {
        const int m = bm0 + wm + mt * 16 + rb + i;
        O[(size_t)m * 1024 + n] = acc[mt][nt][i] + bvv;
      }
    }
  }
}

// ---------------------------------------------------------------------------
extern "C" void kernel_launch(void* const* d_in, const int* in_sizes, int n_in,
                              void* d_out, int out_size, void* d_ws, size_t ws_size,
                              hipStream_t stream)
{
  const float* query = (const float*)d_in[0];
  const float* key   = (const float*)d_in[1];
  const float* value = (const float*)d_in[2];
  const float* Wq = (const float*)d_in[3];
  const float* bq = (const float*)d_in[4];
  const float* Wk = (const float*)d_in[5];
  const float* bk = (const float*)d_in[6];
  const float* Wv = (const float*)d_in[7];
  const float* bv = (const float*)d_in[8];
  const float* Wo = (const float*)d_in[9];
  const float* bo = (const float*)d_in[10];

  float* out = (float*)d_out;
  float* amax_out = out + (size_t)8 * 1024 * 1024;  // out is [8,1024,1024] f32 first

  char* wsb = (char*)d_ws;
  __bf16* qp  = (__bf16*)wsb;                                 // 16MB
  __bf16* kp  = (__bf16*)(wsb + ((size_t)16 << 20));          // 16MB
  __bf16* vpT = (__bf16*)(wsb + ((size_t)32 << 20));          // 16MB [B][H][D][S']
  // rep: own slot if ws allows, else alias qp (safe: head h reads qp cols h*64
  // strictly before rep cols h*64 are written; rows are block-exclusive).
  __bf16* rep = (ws_size >= ((size_t)64 << 20)) ? (__bf16*)(wsb + ((size_t)48 << 20)) : qp;

  dim3 gG(8, 64);
  proj_gemm<0><<<gG, 256, 0, stream>>>(query, Wq, bq, qp, 0.125f);  // D^-0.5 folded
  proj_gemm<0><<<gG, 256, 0, stream>>>(key,   Wk, bk, kp, 1.0f);
  proj_gemm<1><<<gG, 256, 0, stream>>>(value, Wv, bv, vpT, 1.0f);
  attn_kernel<<<512, 512, 0, stream>>>(qp, kp, vpT, rep, amax_out);
  out_gemm<<<gG, 256, 0, stream>>>(rep, Wo, bo, out);
}